// Round 1
// baseline (251.778 us; speedup 1.0000x reference)
//
#include <hip/hip_runtime.h>

// RoIAlign forward, MI355X.
// Shapes: features (4,256,200,200) fp32 NCHW, rois (512,5) fp32,
// out (512,256,7,7) fp32. OUT 7x7, sampling S=2, scale 0.25.
//
// Strategy: block = (roi, 16-channel chunk). Per block:
//  1) 28 threads compute per-axis sample metadata (idx lo/hi, lerp weights,
//     valid mask) into LDS — identical semantics to the JAX reference
//     (_axis_weights: clip to [0, limit-1], floor, +1 capped, valid in
//     [-1, limit]).
//  2) Stage the ROI's feature footprint (<=27x27, guaranteed <=~25 by the
//     ROI size bounds: wh<=96 img px * 0.25 = 24 feat px) for 16 channels
//     into LDS. Global reads are x-contiguous row segments (coalesced);
//     LDS stride PAD=17 (gcd(17,32)=1) keeps writes/reads <=2-way banked.
//  3) Each thread (c = tid&15, slot = tid>>4) computes bins slot,slot+16,...
//     16 LDS taps per output bin, avg of 2x2 samples.

#define OH 7
#define OW 7
#define NSAMP 14          // OH*2 == OW*2
#define NB 4
#define CH 256
#define FH 200
#define FW 200
#define NR 512
#define CCH 16            // channels per chunk
#define NCHUNK (CH / CCH) // 16
#define PAD 17            // LDS channel stride (16 data + 1 pad)
#define MAXF 27           // max footprint extent (data bound ~25)
#define BLK 256

__global__ __launch_bounds__(BLK) void roialign_fwd(
    const float* __restrict__ feat,
    const float* __restrict__ rois,
    float* __restrict__ out)
{
    __shared__ float tile[MAXF * MAXF * PAD];       // ~49.6 KB
    __shared__ int   s_il[2][NSAMP];                // axis 0 = y, 1 = x
    __shared__ int   s_ih[2][NSAMP];
    __shared__ float s_w0[2][NSAMP];
    __shared__ float s_w1[2][NSAMP];

    const int block = blockIdx.x;
    const int r     = block >> 4;       // roi index
    const int chunk = block & (NCHUNK - 1);
    const int c0    = chunk * CCH;
    const int tid   = threadIdx.x;

    // ---- ROI params (wave-uniform scalar loads) ----
    const int   b  = (int)rois[r * 5 + 0];
    const float x1 = rois[r * 5 + 1] * 0.25f;
    const float y1 = rois[r * 5 + 2] * 0.25f;
    const float x2 = rois[r * 5 + 3] * 0.25f;
    const float y2 = rois[r * 5 + 4] * 0.25f;
    const float roi_w = fmaxf(x2 - x1, 1.0f);
    const float roi_h = fmaxf(y2 - y1, 1.0f);
    const float bw = roi_w * (1.0f / OW);
    const float bh = roi_h * (1.0f / OH);

    // ---- per-axis sample metadata ----
    if (tid < 2 * NSAMP) {
        const int axis = tid >= NSAMP;           // 0 = y, 1 = x
        const int i    = tid - axis * NSAMP;
        const float start = axis ? x1 : y1;
        const float bsz   = axis ? bw : bh;
        // y = start + ((i + 0.5)/2) * bin_size
        const float pos   = start + (i + 0.5f) * 0.5f * bsz;
        const float valid = (pos >= -1.0f && pos <= 200.0f) ? 1.0f : 0.0f;
        const float pc    = fminf(fmaxf(pos, 0.0f), 199.0f);
        const int   il    = (int)floorf(pc);
        const int   ih    = min(il + 1, 199);
        const float l     = pc - (float)il;
        s_il[axis][i] = il;
        s_ih[axis][i] = ih;
        s_w0[axis][i] = (1.0f - l) * valid;
        s_w1[axis][i] = l * valid;
    }
    __syncthreads();

    // footprint bounds: sample coords are monotone in i, so min = idx[0].lo,
    // max = idx[13].hi
    const int ylo = s_il[0][0];
    const int xlo = s_il[1][0];
    int fh = s_ih[0][NSAMP - 1] - ylo + 1;
    int fw = s_ih[1][NSAMP - 1] - xlo + 1;
    fh = min(fh, MAXF);   // safety clamp; never triggers for this data
    fw = min(fw, MAXF);

    // ---- stage footprint for CCH channels into LDS ----
    {
        const int tx = tid & 31;
        const int ty = tid >> 5;                  // 0..7
        const float* fbase =
            feat + ((size_t)(b * CH + c0) * FH + ylo) * FW + xlo;
        for (int y = ty; y < fh; y += BLK / 32) {
            for (int x = tx; x < fw; x += 32) {
                const float* g = fbase + y * FW + x;
                float* l = tile + (y * fw + x) * PAD;
                #pragma unroll
                for (int c = 0; c < CCH; c++) {
                    l[c] = g[(size_t)c * (FH * FW)];
                }
            }
        }
    }
    __syncthreads();

    // ---- compute: thread = (channel cl, bin slot) ----
    const int cl   = tid & (CCH - 1);
    const int slot = tid >> 4;                    // 0..15
    const float* tc = tile + cl;

    for (int bin = slot; bin < OH * OW; bin += BLK / CCH) {
        const int ph = bin / OW;
        const int pw = bin - ph * OW;
        float acc = 0.0f;
        #pragma unroll
        for (int sy = 0; sy < 2; sy++) {
            const int gy = ph * 2 + sy;
            const int rowl = (s_il[0][gy] - ylo) * fw;
            const int rowh = (s_ih[0][gy] - ylo) * fw;
            const float wy0 = s_w0[0][gy];
            const float wy1 = s_w1[0][gy];
            #pragma unroll
            for (int sx = 0; sx < 2; sx++) {
                const int gx = pw * 2 + sx;
                const int ixl = s_il[1][gx] - xlo;
                const int ixh = s_ih[1][gx] - xlo;
                const float wx0 = s_w0[1][gx];
                const float wx1 = s_w1[1][gx];
                const float v00 = tc[(rowl + ixl) * PAD];
                const float v01 = tc[(rowl + ixh) * PAD];
                const float v10 = tc[(rowh + ixl) * PAD];
                const float v11 = tc[(rowh + ixh) * PAD];
                acc += wy0 * (wx0 * v00 + wx1 * v01)
                     + wy1 * (wx0 * v10 + wx1 * v11);
            }
        }
        out[(size_t)(r * CH + c0 + cl) * (OH * OW) + bin] = acc * 0.25f;
    }
}

extern "C" void kernel_launch(void* const* d_in, const int* in_sizes, int n_in,
                              void* d_out, int out_size, void* d_ws, size_t ws_size,
                              hipStream_t stream) {
    const float* feat = (const float*)d_in[0];
    const float* rois = (const float*)d_in[1];
    float* out = (float*)d_out;
    roialign_fwd<<<NR * NCHUNK, BLK, 0, stream>>>(feat, rois, out);
}